// Round 5
// baseline (147.086 us; speedup 1.0000x reference)
//
#include <hip/hip_runtime.h>

// mean(( (model-cur)/3 - 0.0257*Lap3D(cur) - src(cur) )^2) over [8,1,128,128,128] f32.
// Zero-padded 7-point stencil.
//
// Thread tid owns (z,y,x4) fixed across all 8 batches (stride 2^21 elements).
// Boundary handling precomputed: clamped offsets + 0/1 float masks => all loads
// unconditional. Software-pipelined register double-buffer: the next pair of
// batches' 12 float4 loads are issued BEFORE computing the current pair, so
// ~12 loads stay in flight for the whole wave lifetime (fixes the ~50% memory
// duty cycle seen in R4: 44us at only 3 TB/s effective with VALUBusy 14%).

constexpr int WW = 128;
constexpr int HH = 128;
constexpr long long N_ELEM = 8LL * 128 * 128 * 128;   // 16,777,216
constexpr int NBLOCKS = 2048;

constexpr float ALPHA  = 0.0257f;
constexpr float INV_DT = 1.0f / 3.0f;
constexpr float SRC_I  = 100000.0f;
constexpr float THRESH = 1000.0f;

struct T6 { float4 c, m, ym, yp, zm, zp; };

__device__ __forceinline__ T6 load6(const float* __restrict__ cur,
                                    const float* __restrict__ model, int i,
                                    int oym, int oyp, int ozm, int ozp) {
    T6 t;
    t.c  = *reinterpret_cast<const float4*>(cur + i);
    t.m  = *reinterpret_cast<const float4*>(model + i);
    t.ym = *reinterpret_cast<const float4*>(cur + i + oym);
    t.yp = *reinterpret_cast<const float4*>(cur + i + oyp);
    t.zm = *reinterpret_cast<const float4*>(cur + i + ozm);
    t.zp = *reinterpret_cast<const float4*>(cur + i + ozp);
    return t;
}

__device__ __forceinline__ float sq_residual4(
        const T6& t,
        const float fym, const float fyp, const float fzm, const float fzp,
        const bool x_lo, const bool x_hi, float acc) {
    // x-neighbors via wave shuffle; lanes with x4==0 are lanes {0,32}, x4==31 are
    // {31,63}, so the 32-lane-boundary leak is always masked.
    float left  = __shfl_up(t.c.w, 1, 64);
    float right = __shfl_down(t.c.x, 1, 64);
    if (x_lo) left = 0.0f;
    if (x_hi) right = 0.0f;

    const float cc[4]  = {t.c.x, t.c.y, t.c.z, t.c.w};
    const float mm[4]  = {t.m.x, t.m.y, t.m.z, t.m.w};
    const float xs[6]  = {left, t.c.x, t.c.y, t.c.z, t.c.w, right};
    const float yms[4] = {t.ym.x, t.ym.y, t.ym.z, t.ym.w};
    const float yps[4] = {t.yp.x, t.yp.y, t.yp.z, t.yp.w};
    const float zms[4] = {t.zm.x, t.zm.y, t.zm.z, t.zm.w};
    const float zps[4] = {t.zp.x, t.zp.y, t.zp.z, t.zp.w};

    #pragma unroll
    for (int j = 0; j < 4; ++j) {
        float lap = xs[j] + xs[j + 2] - 6.0f * cc[j];
        lap = fmaf(fym, yms[j], lap);
        lap = fmaf(fyp, yps[j], lap);
        lap = fmaf(fzm, zms[j], lap);
        lap = fmaf(fzp, zps[j], lap);
        const float td  = (mm[j] - cc[j]) * INV_DT;
        const float src = (cc[j] > THRESH) ? SRC_I : 0.0f;
        const float r   = td - ALPHA * lap - src;
        acc = fmaf(r, r, acc);
    }
    return acc;
}

__global__ __launch_bounds__(256) void heat_loss_kernel(
        const float* __restrict__ model,
        const float* __restrict__ cur,
        float* __restrict__ block_sums) {
    const int tid = blockIdx.x * blockDim.x + threadIdx.x;   // 0 .. 2^19-1
    const int x4 = tid & 31;
    const int y  = (tid >> 5) & 127;
    const int z  = (tid >> 12) & 127;

    const bool x_lo = (x4 == 0);
    const bool x_hi = (x4 == 31);
    const float fym = (y == 0)   ? 0.0f : 1.0f;
    const float fyp = (y == 127) ? 0.0f : 1.0f;
    const float fzm = (z == 0)   ? 0.0f : 1.0f;
    const float fzp = (z == 127) ? 0.0f : 1.0f;
    const int oym = (y == 0)   ? 0 : -WW;
    const int oyp = (y == 127) ? 0 :  WW;
    const int ozm = (z == 0)   ? 0 : -HH * WW;
    const int ozp = (z == 127) ? 0 :  HH * WW;

    const int i = (z * HH + y) * WW + x4 * 4;   // batch-0 index; +2^21 per batch

    float acc = 0.0f;

    // prologue: batches 0,1 in flight
    T6 a0 = load6(cur, model, i,             oym, oyp, ozm, ozp);
    T6 a1 = load6(cur, model, i + (1 << 21), oym, oyp, ozm, ozp);

    #pragma unroll 1
    for (int bb = 1; bb < 4; ++bb) {
        const int j = i + (bb << 22);
        // issue next pair's 12 loads before touching the current pair
        T6 b0 = load6(cur, model, j,             oym, oyp, ozm, ozp);
        T6 b1 = load6(cur, model, j + (1 << 21), oym, oyp, ozm, ozp);

        acc = sq_residual4(a0, fym, fyp, fzm, fzp, x_lo, x_hi, acc);
        acc = sq_residual4(a1, fym, fyp, fzm, fzp, x_lo, x_hi, acc);

        a0 = b0;
        a1 = b1;
    }

    // epilogue: batches 6,7
    acc = sq_residual4(a0, fym, fyp, fzm, fzp, x_lo, x_hi, acc);
    acc = sq_residual4(a1, fym, fyp, fzm, fzp, x_lo, x_hi, acc);

    // 64-lane wave reduction
    #pragma unroll
    for (int off = 32; off > 0; off >>= 1)
        acc += __shfl_down(acc, off, 64);

    __shared__ float wsum[4];
    const int lane = threadIdx.x & 63;
    const int wave = threadIdx.x >> 6;
    if (lane == 0) wsum[wave] = acc;
    __syncthreads();

    if (threadIdx.x == 0)
        block_sums[blockIdx.x] = wsum[0] + wsum[1] + wsum[2] + wsum[3];
}

__global__ __launch_bounds__(256) void finalize_kernel(
        const float* __restrict__ block_sums, float* __restrict__ out) {
    double a = 0.0;
    for (int j = threadIdx.x; j < NBLOCKS; j += 256)
        a += (double)block_sums[j];

    #pragma unroll
    for (int off = 32; off > 0; off >>= 1)
        a += __shfl_down(a, off, 64);

    __shared__ double wsum[4];
    const int lane = threadIdx.x & 63;
    const int wave = threadIdx.x >> 6;
    if (lane == 0) wsum[wave] = a;
    __syncthreads();

    if (threadIdx.x == 0)
        out[0] = (float)((wsum[0] + wsum[1] + wsum[2] + wsum[3]) / (double)N_ELEM);
}

extern "C" void kernel_launch(void* const* d_in, const int* in_sizes, int n_in,
                              void* d_out, int out_size, void* d_ws, size_t ws_size,
                              hipStream_t stream) {
    const float* model = (const float*)d_in[0];   // model_output
    const float* cur   = (const float*)d_in[1];   // current_input
    float* block_sums = (float*)d_ws;             // NBLOCKS floats, fully written each call
    float* out = (float*)d_out;

    heat_loss_kernel<<<NBLOCKS, 256, 0, stream>>>(model, cur, block_sums);
    finalize_kernel<<<1, 256, 0, stream>>>(block_sums, out);
}

// Round 6
// 145.896 us; speedup vs baseline: 1.0082x; 1.0082x over previous
//
#include <hip/hip_runtime.h>

// mean(( (model-cur)/3 - 0.0257*Lap3D(cur) - src(cur) )^2) over [8,1,128,128,128] f32.
// Zero-padded 7-point stencil.
//
// Thread tid owns (z,y,x4) fixed across all 8 batches (stride 2^21 elements).
// Boundary handling precomputed (clamped offsets + 0/1 masks) => unconditional loads.
// R5 lesson: a source-level register double-buffer gets DEFEATED by the compiler
// (loads sink to just before use; VGPR stayed 48). This version pins the pipeline
// with __builtin_amdgcn_sched_barrier(0) after each prefetch-issue block: the next
// group's 12 float4 loads cannot sink below it, so they stay in flight during the
// current group's compute. Expect VGPR ~120; if it drops to ~48 the pin failed.

constexpr int WW = 128;
constexpr int HH = 128;
constexpr long long N_ELEM = 8LL * 128 * 128 * 128;   // 16,777,216
constexpr int NBLOCKS = 2048;

constexpr float ALPHA  = 0.0257f;
constexpr float INV_DT = 1.0f / 3.0f;
constexpr float SRC_I  = 100000.0f;
constexpr float THRESH = 1000.0f;

struct T6 { float4 c, m, ym, yp, zm, zp; };

__device__ __forceinline__ T6 load6(const float* __restrict__ cur,
                                    const float* __restrict__ model, int i,
                                    int oym, int oyp, int ozm, int ozp) {
    T6 t;
    t.c  = *reinterpret_cast<const float4*>(cur + i);
    t.m  = *reinterpret_cast<const float4*>(model + i);
    t.ym = *reinterpret_cast<const float4*>(cur + i + oym);
    t.yp = *reinterpret_cast<const float4*>(cur + i + oyp);
    t.zm = *reinterpret_cast<const float4*>(cur + i + ozm);
    t.zp = *reinterpret_cast<const float4*>(cur + i + ozp);
    return t;
}

__device__ __forceinline__ float sq_residual4(
        const T6& t,
        const float fym, const float fyp, const float fzm, const float fzp,
        const bool x_lo, const bool x_hi, float acc) {
    // x-neighbors via wave shuffle; lanes with x4==0 are lanes {0,32}, x4==31 are
    // {31,63}, so the 32-lane-boundary leak is always masked.
    float left  = __shfl_up(t.c.w, 1, 64);
    float right = __shfl_down(t.c.x, 1, 64);
    if (x_lo) left = 0.0f;
    if (x_hi) right = 0.0f;

    const float cc[4]  = {t.c.x, t.c.y, t.c.z, t.c.w};
    const float mm[4]  = {t.m.x, t.m.y, t.m.z, t.m.w};
    const float xs[6]  = {left, t.c.x, t.c.y, t.c.z, t.c.w, right};
    const float yms[4] = {t.ym.x, t.ym.y, t.ym.z, t.ym.w};
    const float yps[4] = {t.yp.x, t.yp.y, t.yp.z, t.yp.w};
    const float zms[4] = {t.zm.x, t.zm.y, t.zm.z, t.zm.w};
    const float zps[4] = {t.zp.x, t.zp.y, t.zp.z, t.zp.w};

    #pragma unroll
    for (int j = 0; j < 4; ++j) {
        float lap = xs[j] + xs[j + 2] - 6.0f * cc[j];
        lap = fmaf(fym, yms[j], lap);
        lap = fmaf(fyp, yps[j], lap);
        lap = fmaf(fzm, zms[j], lap);
        lap = fmaf(fzp, zps[j], lap);
        const float td  = (mm[j] - cc[j]) * INV_DT;
        const float src = (cc[j] > THRESH) ? SRC_I : 0.0f;
        const float r   = td - ALPHA * lap - src;
        acc = fmaf(r, r, acc);
    }
    return acc;
}

__global__ __launch_bounds__(256) void heat_loss_kernel(
        const float* __restrict__ model,
        const float* __restrict__ cur,
        float* __restrict__ block_sums) {
    const int tid = blockIdx.x * blockDim.x + threadIdx.x;   // 0 .. 2^19-1
    const int x4 = tid & 31;
    const int y  = (tid >> 5) & 127;
    const int z  = (tid >> 12) & 127;

    const bool x_lo = (x4 == 0);
    const bool x_hi = (x4 == 31);
    const float fym = (y == 0)   ? 0.0f : 1.0f;
    const float fyp = (y == 127) ? 0.0f : 1.0f;
    const float fzm = (z == 0)   ? 0.0f : 1.0f;
    const float fzp = (z == 127) ? 0.0f : 1.0f;
    const int oym = (y == 0)   ? 0 : -WW;
    const int oyp = (y == 127) ? 0 :  WW;
    const int ozm = (z == 0)   ? 0 : -HH * WW;
    const int ozp = (z == 127) ? 0 :  HH * WW;

    const int i = (z * HH + y) * WW + x4 * 4;   // batch-0 index; +2^21 per batch

    float acc = 0.0f;

    // prologue: group 0 (batches 0,1) in flight
    T6 t0 = load6(cur, model, i,             oym, oyp, ozm, ozp);
    T6 t1 = load6(cur, model, i + (1 << 21), oym, oyp, ozm, ozp);

    #pragma unroll 1
    for (int bb = 1; bb < 4; ++bb) {
        const int j = i + (bb << 22);
        // issue next group's 12 loads
        T6 u0 = load6(cur, model, j,             oym, oyp, ozm, ozp);
        T6 u1 = load6(cur, model, j + (1 << 21), oym, oyp, ozm, ozp);

        // scheduling fence: the 12 loads above may NOT sink below this point,
        // and the compute below may not hoist above it. Keeps 12 loads in
        // flight during compute; forces both buffers live (~24 float4).
        __builtin_amdgcn_sched_barrier(0);

        acc = sq_residual4(t0, fym, fyp, fzm, fzp, x_lo, x_hi, acc);
        acc = sq_residual4(t1, fym, fyp, fzm, fzp, x_lo, x_hi, acc);

        t0 = u0;
        t1 = u1;
    }

    // epilogue: batches 6,7
    acc = sq_residual4(t0, fym, fyp, fzm, fzp, x_lo, x_hi, acc);
    acc = sq_residual4(t1, fym, fyp, fzm, fzp, x_lo, x_hi, acc);

    // 64-lane wave reduction
    #pragma unroll
    for (int off = 32; off > 0; off >>= 1)
        acc += __shfl_down(acc, off, 64);

    __shared__ float wsum[4];
    const int lane = threadIdx.x & 63;
    const int wave = threadIdx.x >> 6;
    if (lane == 0) wsum[wave] = acc;
    __syncthreads();

    if (threadIdx.x == 0)
        block_sums[blockIdx.x] = wsum[0] + wsum[1] + wsum[2] + wsum[3];
}

__global__ __launch_bounds__(256) void finalize_kernel(
        const float* __restrict__ block_sums, float* __restrict__ out) {
    double a = 0.0;
    for (int j = threadIdx.x; j < NBLOCKS; j += 256)
        a += (double)block_sums[j];

    #pragma unroll
    for (int off = 32; off > 0; off >>= 1)
        a += __shfl_down(a, off, 64);

    __shared__ double wsum[4];
    const int lane = threadIdx.x & 63;
    const int wave = threadIdx.x >> 6;
    if (lane == 0) wsum[wave] = a;
    __syncthreads();

    if (threadIdx.x == 0)
        out[0] = (float)((wsum[0] + wsum[1] + wsum[2] + wsum[3]) / (double)N_ELEM);
}

extern "C" void kernel_launch(void* const* d_in, const int* in_sizes, int n_in,
                              void* d_out, int out_size, void* d_ws, size_t ws_size,
                              hipStream_t stream) {
    const float* model = (const float*)d_in[0];   // model_output
    const float* cur   = (const float*)d_in[1];   // current_input
    float* block_sums = (float*)d_ws;             // NBLOCKS floats, fully written each call
    float* out = (float*)d_out;

    heat_loss_kernel<<<NBLOCKS, 256, 0, stream>>>(model, cur, block_sums);
    finalize_kernel<<<1, 256, 0, stream>>>(block_sums, out);
}

// Round 8
// 134.602 us; speedup vs baseline: 1.0927x; 1.0839x over previous
//
#include <hip/hip_runtime.h>

// mean(( (model-cur)/3 - 0.0257*Lap3D(cur) - src(cur) )^2) over [8,1,128,128,128] f32.
// Zero-padded 7-point stencil.
//
// R6 lesson: per-wave software pipelining materialized (VGPR 84) but time was
// unchanged -> not latency-bound per wave; bound by L1-miss traffic (~268 MB:
// c+m+zm+zp; ym/yp already L1-hit within the 8-row block slab).
// This version: register z-march. Block = (x4:32, yr:8) slab, fixed batch,
// marches a 16-plane z-chunk. zm/c carried in registers; per step only
// {zp, m, ym, yp} are loaded (ym/yp are L1 hits on the block's own planes).
// L1-miss demand drops to ~150 MB. model is loaded non-temporally so its
// one-time stream doesn't evict reused cur planes from L1.

constexpr int WW = 128;
constexpr int HH = 128;
constexpr int DD = 128;
constexpr int PLANE = HH * WW;                        // 16384 floats
constexpr long long N_ELEM = 8LL * DD * HH * WW;      // 16,777,216
constexpr int ZCHUNK = 16;
constexpr int NBLOCKS = 8 * 16 * (DD / ZCHUNK);       // batch * yslabs * zchunks = 1024

constexpr float ALPHA  = 0.0257f;
constexpr float INV_DT = 1.0f / 3.0f;
constexpr float SRC_I  = 100000.0f;
constexpr float THRESH = 1000.0f;

typedef float f32x4 __attribute__((ext_vector_type(4)));

struct L4 { float4 zp, m, ym, yp; };

__device__ __forceinline__ float4 ldg4(const float* p) {
    return *reinterpret_cast<const float4*>(p);
}
__device__ __forceinline__ float4 ldnt4(const float* p) {
    f32x4 v = __builtin_nontemporal_load(reinterpret_cast<const f32x4*>(p));
    return make_float4(v.x, v.y, v.z, v.w);
}

__device__ __forceinline__ L4 load_step(const float* __restrict__ cur,
                                        const float* __restrict__ model,
                                        int i, int ozp, int oym, int oyp) {
    L4 t;
    t.zp = ldg4(cur + i + ozp);
    t.m  = ldnt4(model + i);
    t.ym = ldg4(cur + i + oym);
    t.yp = ldg4(cur + i + oyp);
    return t;
}

__device__ __forceinline__ float sq_residual4(
        const float4 c, const float4 m,
        const float4 ym, const float4 yp,
        const float4 zm, const float4 zp,
        const float fym, const float fyp, const float fzm, const float fzp,
        const bool x_lo, const bool x_hi, float acc) {
    // x-neighbors via wave shuffle. thread = x4 + 32*yr, so lanes with x4==0 are
    // exactly {0,32} and x4==31 are {31,63}: the 32-lane-boundary leak is masked.
    float left  = __shfl_up(c.w, 1, 64);
    float right = __shfl_down(c.x, 1, 64);
    if (x_lo) left = 0.0f;
    if (x_hi) right = 0.0f;

    const float cc[4]  = {c.x, c.y, c.z, c.w};
    const float mm[4]  = {m.x, m.y, m.z, m.w};
    const float xs[6]  = {left, c.x, c.y, c.z, c.w, right};
    const float yms[4] = {ym.x, ym.y, ym.z, ym.w};
    const float yps[4] = {yp.x, yp.y, yp.z, yp.w};
    const float zms[4] = {zm.x, zm.y, zm.z, zm.w};
    const float zps[4] = {zp.x, zp.y, zp.z, zp.w};

    #pragma unroll
    for (int j = 0; j < 4; ++j) {
        float lap = xs[j] + xs[j + 2] - 6.0f * cc[j];
        lap = fmaf(fym, yms[j], lap);
        lap = fmaf(fyp, yps[j], lap);
        lap = fmaf(fzm, zms[j], lap);
        lap = fmaf(fzp, zps[j], lap);
        const float td  = (mm[j] - cc[j]) * INV_DT;
        const float src = (cc[j] > THRESH) ? SRC_I : 0.0f;
        const float r   = td - ALPHA * lap - src;
        acc = fmaf(r, r, acc);
    }
    return acc;
}

__global__ __launch_bounds__(256) void heat_loss_kernel(
        const float* __restrict__ model,
        const float* __restrict__ cur,
        float* __restrict__ block_sums) {
    const int bx = blockIdx.x;
    const int zc = bx & 7;                 // z-chunk 0..7
    const int ys = (bx >> 3) & 15;         // y-slab  0..15
    const int b  = bx >> 7;                // batch   0..7
    const int z0 = zc * ZCHUNK;

    const int x4 = threadIdx.x & 31;
    const int yr = threadIdx.x >> 5;       // 0..7
    const int y  = ys * 8 + yr;

    const bool x_lo = (x4 == 0);
    const bool x_hi = (x4 == 31);
    const float fym = (y == 0)   ? 0.0f : 1.0f;
    const float fyp = (y == 127) ? 0.0f : 1.0f;
    const int oym = (y == 0)   ? 0 : -WW;
    const int oyp = (y == 127) ? 0 :  WW;

    int i = ((b * DD + z0) * HH + y) * WW + x4 * 4;

    // prologue: zm, c planes into registers
    const int ozm0 = (z0 == 0) ? 0 : -PLANE;
    float fzm = (z0 == 0) ? 0.0f : 1.0f;
    float4 zm = ldg4(cur + i + ozm0);
    float4 c  = ldg4(cur + i);

    // step-0 loads (zp, m, ym, yp); last chunk's final step clamps zp
    L4 t0 = load_step(cur, model, i, PLANE, oym, oyp);

    float acc = 0.0f;

    #pragma unroll 1
    for (int s = 0; s < ZCHUNK - 1; ++s) {
        const int zz1 = z0 + s + 1;                      // next step's z
        const int ozp1 = (zz1 == 127) ? 0 : PLANE;
        // issue next step's 4 loads
        L4 t1 = load_step(cur, model, i + PLANE, ozp1, oym, oyp);

        // pin: loads above may not sink below; compute may not hoist above.
        __builtin_amdgcn_sched_barrier(0);

        acc = sq_residual4(c, t0.m, t0.ym, t0.yp, zm, t0.zp,
                           fym, fyp, fzm, 1.0f, x_lo, x_hi, acc);
        zm = c;
        c  = t0.zp;
        fzm = 1.0f;
        t0 = t1;
        i += PLANE;
    }

    // final step of the chunk (z = z0+15); zp weight 0 iff z==127
    const float fzp_last = (z0 + ZCHUNK - 1 == 127) ? 0.0f : 1.0f;
    acc = sq_residual4(c, t0.m, t0.ym, t0.yp, zm, t0.zp,
                       fym, fyp, fzm, fzp_last, x_lo, x_hi, acc);

    // 64-lane wave reduction
    #pragma unroll
    for (int off = 32; off > 0; off >>= 1)
        acc += __shfl_down(acc, off, 64);

    __shared__ float wsum[4];
    const int lane = threadIdx.x & 63;
    const int wave = threadIdx.x >> 6;
    if (lane == 0) wsum[wave] = acc;
    __syncthreads();

    if (threadIdx.x == 0)
        block_sums[blockIdx.x] = wsum[0] + wsum[1] + wsum[2] + wsum[3];
}

__global__ __launch_bounds__(256) void finalize_kernel(
        const float* __restrict__ block_sums, float* __restrict__ out) {
    double a = 0.0;
    for (int j = threadIdx.x; j < NBLOCKS; j += 256)
        a += (double)block_sums[j];

    #pragma unroll
    for (int off = 32; off > 0; off >>= 1)
        a += __shfl_down(a, off, 64);

    __shared__ double wsum[4];
    const int lane = threadIdx.x & 63;
    const int wave = threadIdx.x >> 6;
    if (lane == 0) wsum[wave] = a;
    __syncthreads();

    if (threadIdx.x == 0)
        out[0] = (float)((wsum[0] + wsum[1] + wsum[2] + wsum[3]) / (double)N_ELEM);
}

extern "C" void kernel_launch(void* const* d_in, const int* in_sizes, int n_in,
                              void* d_out, int out_size, void* d_ws, size_t ws_size,
                              hipStream_t stream) {
    const float* model = (const float*)d_in[0];   // model_output
    const float* cur   = (const float*)d_in[1];   // current_input
    float* block_sums = (float*)d_ws;             // NBLOCKS floats, fully written each call
    float* out = (float*)d_out;

    heat_loss_kernel<<<NBLOCKS, 256, 0, stream>>>(model, cur, block_sums);
    finalize_kernel<<<1, 256, 0, stream>>>(block_sums, out);
}